// Round 20
// baseline (61.894 us; speedup 1.0000x reference)
//
#include <hip/hip_runtime.h>
#include <hip/hip_bf16.h>

typedef unsigned char u8;
typedef unsigned int u32;
typedef unsigned long long u64;
typedef __attribute__((ext_vector_type(4))) float f32x4;

#define B_SZ 4096
#define D_SZ 512
#define NCLS 64
#define BK   64                      // 64 fp8 = 64 B per row per K-step
#define NKK  (D_SZ / BK)             // 8 K-steps
#define NT   32                      // 4096/128 tiles per dimension
#define NBLK (NT * (NT + 1) / 2)     // 528 lower-triangular tiles (528 % 8 == 0)
#define TILE_BYTES (128 * BK)        // 8 KB per K-slice panel

// full-depth counted-vmcnt: all 32 gloads issued up front (4 per K-step:
// A-slice 2 + B-slice 2); step k waits until its 4 have landed.
#define WAITN(n)  asm volatile("s_waitcnt vmcnt(" #n ")" ::: "memory")
#define BARRIER() asm volatile("s_barrier" ::: "memory")

// ---------------- helpers ----------------

// fp32 -> OCP e4m3fn (bias 7, max 448, no inf), RNE; FTZ below 2^-6.
// R14-proven on this problem: absmax 0.0.
__device__ __forceinline__ u8 f2fp8(float x) {
    union { float f; u32 u; } a; a.f = x;
    u32 s = (a.u >> 24) & 0x80u;
    u32 m = a.u & 0x7fffffffu;
    u32 r = m + 0x7ffffu + ((m >> 20) & 1u);   // RNE into 3-bit mantissa
    int e = (int)(r >> 23) - 127 + 7;          // fp8 biased exponent
    u32 mant = (r >> 20) & 7u;
    if (e <= 0) return (u8)s;                  // FTZ (|x| < 2^-6)
    if (e >= 16) return (u8)(s | 0x7Eu);       // clamp to 448 (never NaN 0x7F)
    return (u8)(s | ((u32)e << 3) | mant);
}

__device__ __forceinline__ void gload16(const void* g, void* l) {
    // async global -> LDS, 16 bytes per lane; LDS dest = wave-uniform base + lane*16
    __builtin_amdgcn_global_load_lds(
        (const __attribute__((address_space(1))) u32*)g,
        (__attribute__((address_space(3))) u32*)l,
        16, 0, 0);
}

// Stage one 128x64B fp8 K-slice (8 KB) into LDS, XOR-pre-swizzling the GLOBAL
// source 16B-chunk. chunk' = chunk ^ (row & 3). 2 gloads per thread (256 thr).
// Byte-identical addressing to the R14 champion.
__device__ __forceinline__ void stage_fp8(const u8* __restrict__ gsrc, u8* dst, int t) {
    #pragma unroll
    for (int q = 0; q < 2; ++q) {
        const int s = t + q * 256;
        const int r = s >> 2;                        // row 0..127
        const int c16 = (s & 3) ^ (r & 3);           // swizzled 16B chunk within row
        gload16(gsrc + (size_t)r * D_SZ + (c16 << 4), dst + s * 16);
    }
}

// ---------------- kernel 1: fp32->fp8 copy, row sq-norms (exact fp32), init ----------------

__global__ __launch_bounds__(256) void prep_kernel(
    const float* __restrict__ in, u8* __restrict__ bf8,
    float* __restrict__ sq, float* __restrict__ ap_sum, u32* __restrict__ an_min)
{
    const int wave = threadIdx.x >> 6, l = threadIdx.x & 63;
    const int row = blockIdx.x * 4 + wave;
    const float* p = in + (size_t)row * D_SZ + l * 8;
    float4 v0 = *(const float4*)p;
    float4 v1 = *(const float4*)(p + 4);
    float s = v0.x*v0.x + v0.y*v0.y + v0.z*v0.z + v0.w*v0.w
            + v1.x*v1.x + v1.y*v1.y + v1.z*v1.z + v1.w*v1.w;
    u64 pk =  (u64)f2fp8(v0.x)
           | ((u64)f2fp8(v0.y) << 8)
           | ((u64)f2fp8(v0.z) << 16)
           | ((u64)f2fp8(v0.w) << 24)
           | ((u64)f2fp8(v1.x) << 32)
           | ((u64)f2fp8(v1.y) << 40)
           | ((u64)f2fp8(v1.z) << 48)
           | ((u64)f2fp8(v1.w) << 56);
    *(u64*)(bf8 + (size_t)row * D_SZ + l * 8) = pk;
    #pragma unroll
    for (int off = 1; off < 64; off <<= 1) s += __shfl_xor(s, off);
    if (l == 0) {
        sq[row] = s;
        ap_sum[row] = 0.0f;
        an_min[row] = 0x7f800000u;   // +inf bits
    }
}

// ---------------- kernel 2: fp8 Gram, FULL-K single-fill pipeline ----------------
// All 8 K-slices of both panels (128 KB) staged in ONE up-front burst of 32
// gloads/thread (32 KB in flight per wave — 8x deeper than the champion's
// depth-2). The K-loop is then PURE COMPUTE: progressive counted vmcnt
// (28,24,...,0) + one barrier per step, zero mid-loop staging. This decouples
// load issue from the wait/barrier chain — the hypothesized 2.2 TB/s
// staging-rate wall. No LDS overwrites -> no WAR hazards. 130 KB dynamic LDS
// -> 1 block/CU (intentional: queue-depth replaces TLP for latency hiding).

extern __shared__ char smem[];

__global__ __launch_bounds__(256) void tile_kernel(
    const u8* __restrict__ bf8, const int* __restrict__ lab,
    const float* __restrict__ sq, float* __restrict__ ap_sum, u32* __restrict__ an_min)
{
    u8* As = (u8*)smem;                        // 8 slices x 8 KB = 64 KB
    u8* Bs = As + NKK * TILE_BYTES;            // 64 KB
    float* sqA = (float*)(smem + 131072);      // [128]
    float* sqB = sqA + 128;                    // [128]
    int* labA  = (int*)(smem + 132096);        // [128]
    int* labB  = labA + 128;                   // [128]

    const int t = threadIdx.x;

    // XCD-chunked bijective swizzle: 528 % 8 == 0 -> each XCD gets 66 consecutive tiles
    int bid = blockIdx.x;
    bid = (bid & 7) * (NBLK / 8) + (bid >> 3);

    // triangular decode: bid -> (tm, tn), tm >= tn
    int tm = (int)((__builtin_sqrtf(8.0f * (float)bid + 1.0f) - 1.0f) * 0.5f);
    while ((tm + 1) * (tm + 2) / 2 <= bid) ++tm;
    while (tm * (tm + 1) / 2 > bid) --tm;
    const int tn = bid - tm * (tm + 1) / 2;
    const bool diag = (tm == tn);

    const int rowBase = tm * 128;
    const int colBase = tn * 128;

    if (t < 128) { labA[t] = lab[rowBase + t]; sqA[t] = sq[rowBase + t]; }
    else { int u = t - 128; labB[u] = lab[colBase + u]; sqB[u] = sq[colBase + u]; }

    const int wave = t >> 6, lane = t & 63;
    const int wr = wave >> 1, wc = wave & 1;
    const int g = lane >> 4, c = lane & 15;

    f32x4 acc[4][4];
    #pragma unroll
    for (int i = 0; i < 4; ++i)
        #pragma unroll
        for (int j = 0; j < 4; ++j)
            acc[i][j] = (f32x4){0.f, 0.f, 0.f, 0.f};

    const u8* gA = bf8 + (size_t)rowBase * D_SZ;
    const u8* gB = bf8 + (size_t)colBase * D_SZ;

    __syncthreads();   // meta staged + vmcnt baseline 0 before the burst

    // single up-front burst: 4 gloads per K-step (A-slice 2, B-slice 2), K-ordered
    #pragma unroll
    for (int k = 0; k < NKK; ++k) {
        stage_fp8(gA + k * BK, As + k * TILE_BYTES, t);
        stage_fp8(gB + k * BK, Bs + k * TILE_BYTES, t);
    }

    // fragment addressing: lane (c,g) reads 8 fp8 at K byte [ks*32 + g*8, +8) of
    // its row; stored 16B-chunk k16 = ks*2 + (g>>1) is XOR-swizzled by (row&3)=(c&3).
    const int x3 = c & 3, sub = (g & 1) * 8, gh = g >> 1;

    #pragma unroll
    for (int kk = 0; kk < NKK; ++kk) {
        // wait until THIS step's 4 loads landed (own wave); barrier covers other waves
        if      (kk == 0) WAITN(28);
        else if (kk == 1) WAITN(24);
        else if (kk == 2) WAITN(20);
        else if (kk == 3) WAITN(16);
        else if (kk == 4) WAITN(12);
        else if (kk == 5) WAITN(8);
        else if (kk == 6) WAITN(4);
        else              WAITN(0);
        BARRIER();   // all waves passed their wait -> all slices <= kk are in LDS

        const u8* abuf = As + kk * TILE_BYTES;
        const u8* bbuf = Bs + kk * TILE_BYTES;

        #pragma unroll
        for (int ks = 0; ks < 2; ++ks) {
            const int koff = (((ks * 2 + gh) ^ x3) << 4) + sub;
            long a[4], b[4];
            #pragma unroll
            for (int mi = 0; mi < 4; ++mi)
                a[mi] = *(const long*)(abuf + (wr * 64 + mi * 16 + c) * BK + koff);
            #pragma unroll
            for (int ni = 0; ni < 4; ++ni)
                b[ni] = *(const long*)(bbuf + (wc * 64 + ni * 16 + c) * BK + koff);
            #pragma unroll
            for (int mi = 0; mi < 4; ++mi)
                #pragma unroll
                for (int ni = 0; ni < 4; ++ni)
                    acc[mi][ni] = __builtin_amdgcn_mfma_f32_16x16x32_fp8_fp8(a[mi], b[ni], acc[mi][ni], 0, 0, 0);
        }
    }

    // Epilogue. C/D layout: col = lane&15, row = (lane>>4)*4 + reg.
    float sc[4], mc[4];
    #pragma unroll
    for (int ni = 0; ni < 4; ++ni) { sc[ni] = 0.0f; mc[ni] = __builtin_inff(); }

    #pragma unroll
    for (int mi = 0; mi < 4; ++mi) {
        #pragma unroll
        for (int r = 0; r < 4; ++r) {
            const int lrow = wr * 64 + mi * 16 + g * 4 + r;
            const int i = rowBase + lrow;
            const int li = labA[lrow];
            const float sqi = sqA[lrow];
            float s = 0.0f;
            float mn = __builtin_inff();
            #pragma unroll
            for (int ni = 0; ni < 4; ++ni) {
                const int lcol = wc * 64 + ni * 16 + c;
                float d2 = sqi + sqB[lcol] - 2.0f * acc[mi][ni][r];
                d2 = fmaxf(d2, 0.0f);
                float dist = (d2 > 1e-12f) ? __builtin_sqrtf(d2) : 0.0f;
                if (diag && lrow == lcol) dist = 0.0f;   // self distance exactly 0
                if (li == labB[lcol]) { s += dist; sc[ni] += dist; }
                else                  { mn = fminf(mn, dist); mc[ni] = fminf(mc[ni], dist); }
            }
            // row-side: reduce across the 16 c-lanes of this g-group
            #pragma unroll
            for (int off = 1; off < 16; off <<= 1) {
                s += __shfl_xor(s, off);
                mn = fminf(mn, __shfl_xor(mn, off));
            }
            if (c == 0) {
                atomicAdd(&ap_sum[i], s);
                atomicMin(&an_min[i], __float_as_uint(mn));   // dist >= 0: uint order == float order
            }
        }
    }

    if (!diag) {
        // column-side: reduce across the 4 g-groups, then atomic per column
        #pragma unroll
        for (int ni = 0; ni < 4; ++ni) {
            float s = sc[ni], mn = mc[ni];
            s += __shfl_xor(s, 16); s += __shfl_xor(s, 32);
            mn = fminf(mn, __shfl_xor(mn, 16)); mn = fminf(mn, __shfl_xor(mn, 32));
            if (lane < 16) {
                const int j = colBase + wc * 64 + ni * 16 + c;
                atomicAdd(&ap_sum[j], s);
                atomicMin(&an_min[j], __float_as_uint(mn));
            }
        }
    }
}

// ---------------- kernel 3: finalize scalar loss (single block, self-sufficient) ----------------

__global__ __launch_bounds__(1024) void final_kernel(
    const float* __restrict__ ap_sum, const u32* __restrict__ an_min,
    const int* __restrict__ lab, float* __restrict__ out)
{
    __shared__ int cnt[NCLS];
    __shared__ float wsum[16];
    const int t = threadIdx.x;
    if (t < NCLS) cnt[t] = 0;
    __syncthreads();
    for (int i = t; i < B_SZ; i += 1024) atomicAdd(&cnt[lab[i]], 1);
    __syncthreads();
    float v = 0.0f;
    for (int i = t; i < B_SZ; i += 1024) {
        float apm = ap_sum[i] / (float)cnt[lab[i]];
        float anm = __uint_as_float(an_min[i]);
        v += fmaxf(apm - anm + 1.0f, 0.0f);   // MARGIN = 1.0
    }
    #pragma unroll
    for (int off = 1; off < 64; off <<= 1) v += __shfl_xor(v, off);
    if ((t & 63) == 0) wsum[t >> 6] = v;
    __syncthreads();
    if (t == 0) {
        float s = 0.0f;
        #pragma unroll
        for (int w = 0; w < 16; ++w) s += wsum[w];
        out[0] = s;
    }
}

// ---------------- launch ----------------

extern "C" void kernel_launch(void* const* d_in, const int* in_sizes, int n_in,
                              void* d_out, int out_size, void* d_ws, size_t ws_size,
                              hipStream_t stream) {
    const float* inputs = (const float*)d_in[0];
    const int* labels = (const int*)d_in[1];
    float* out = (float*)d_out;

    // workspace layout (~2.1 MB)
    char* ws = (char*)d_ws;
    float* ap_sum = (float*)ws;            // 4096 floats
    u32* an_min = (u32*)(ws + 16384);      // 4096 u32
    float* sq = (float*)(ws + 32768);      // 4096 floats
    u8* bf8 = (u8*)(ws + 65536);           // 4096*512 fp8 = 2 MB

    // dynamic LDS: 128 KB panels + 2 KB meta (R3 precedent: >64 KB dynamic ok)
    const int smem_bytes = NKK * TILE_BYTES * 2 + 2048;   // 133120 B

    prep_kernel<<<dim3(B_SZ / 4), dim3(256), 0, stream>>>(inputs, bf8, sq, ap_sum, an_min);
    tile_kernel<<<dim3(NBLK), dim3(256), smem_bytes, stream>>>(bf8, labels, sq, ap_sum, an_min);
    final_kernel<<<dim3(1), dim3(1024), 0, stream>>>(ap_sum, an_min, labels, out);
}

// Round 21
// 39.426 us; speedup vs baseline: 1.5699x; 1.5699x over previous
//
#include <hip/hip_runtime.h>
#include <hip/hip_bf16.h>

typedef unsigned char u8;
typedef unsigned short u16;
typedef unsigned int u32;
typedef unsigned long long u64;
typedef __attribute__((ext_vector_type(4))) float f32x4;

#define B_SZ 4096
#define D_SZ 512
#define NCLS 64
#define BK   64                      // 64 fp8 = 64 B per row per K-step
#define NKK  (D_SZ / BK)             // 8 K-steps
#define NT   32                      // 4096/128 tiles per dimension
#define NBLK (NT * (NT + 1) / 2)     // 528 lower-triangular tiles (528 % 8 == 0)
#define TILE_BYTES (128 * BK)        // 8 KB per buffer

// counted-vmcnt pipeline primitives (T3/T4: never drain vmcnt to 0 in main loop)
#define WAITV4()  asm volatile("s_waitcnt vmcnt(4)" ::: "memory")
#define WAITV0()  asm volatile("s_waitcnt vmcnt(0)" ::: "memory")
#define BARRIER() asm volatile("s_barrier" ::: "memory")

// ---------------- helpers ----------------

// fp32 -> OCP e4m3fn (bias 7, max 448, no inf), round-to-nearest-even.
// FTZ below 2^-6 — negligible for N(0,1) 512-dots (R14-proven: absmax 0.0).
__device__ __forceinline__ u8 f2fp8(float x) {
    union { float f; u32 u; } a; a.f = x;
    u32 s = (a.u >> 24) & 0x80u;
    u32 m = a.u & 0x7fffffffu;
    u32 r = m + 0x7ffffu + ((m >> 20) & 1u);   // RNE into 3-bit mantissa
    int e = (int)(r >> 23) - 127 + 7;          // fp8 biased exponent
    u32 mant = (r >> 20) & 7u;
    if (e <= 0) return (u8)s;                  // FTZ (|x| < 2^-6)
    if (e >= 16) return (u8)(s | 0x7Eu);       // clamp to 448 (never NaN 0x7F)
    return (u8)(s | ((u32)e << 3) | mant);
}

__device__ __forceinline__ void gload16(const void* g, void* l) {
    // async global -> LDS, 16 bytes per lane; LDS dest = wave-uniform base + lane*16
    __builtin_amdgcn_global_load_lds(
        (const __attribute__((address_space(1))) u32*)g,
        (__attribute__((address_space(3))) u32*)l,
        16, 0, 0);
}

// Stage a 128x64 fp8 tile (8 KB) into LDS, XOR-pre-swizzling the GLOBAL source
// 16B-chunk (4 per row). chunk' = chunk ^ (row & 3). 2 global_load_lds per
// thread (256 thr).
__device__ __forceinline__ void stage_fp8(const u8* __restrict__ gsrc, u8* dst, int t) {
    #pragma unroll
    for (int q = 0; q < 2; ++q) {
        const int s = t + q * 256;
        const int r = s >> 2;                        // row 0..127
        const int c16 = (s & 3) ^ (r & 3);           // swizzled 16B chunk within row
        gload16(gsrc + (size_t)r * D_SZ + (c16 << 4), dst + s * 16);
    }
}

// ---------------- kernel 1: fp32->fp8 copy, row sq-norms (exact fp32), init ----------------

__global__ __launch_bounds__(256) void prep_kernel(
    const float* __restrict__ in, u8* __restrict__ bf8,
    float* __restrict__ sq, float* __restrict__ ap_sum, u32* __restrict__ an_min)
{
    const int wave = threadIdx.x >> 6, l = threadIdx.x & 63;
    const int row = blockIdx.x * 4 + wave;
    const float* p = in + (size_t)row * D_SZ + l * 8;
    float4 v0 = *(const float4*)p;
    float4 v1 = *(const float4*)(p + 4);
    float s = v0.x*v0.x + v0.y*v0.y + v0.z*v0.z + v0.w*v0.w
            + v1.x*v1.x + v1.y*v1.y + v1.z*v1.z + v1.w*v1.w;
    u64 pk =  (u64)f2fp8(v0.x)
           | ((u64)f2fp8(v0.y) << 8)
           | ((u64)f2fp8(v0.z) << 16)
           | ((u64)f2fp8(v0.w) << 24)
           | ((u64)f2fp8(v1.x) << 32)
           | ((u64)f2fp8(v1.y) << 40)
           | ((u64)f2fp8(v1.z) << 48)
           | ((u64)f2fp8(v1.w) << 56);
    *(u64*)(bf8 + (size_t)row * D_SZ + l * 8) = pk;
    #pragma unroll
    for (int off = 1; off < 64; off <<= 1) s += __shfl_xor(s, off);
    if (l == 0) {
        sq[row] = s;
        ap_sum[row] = 0.0f;
        an_min[row] = 0x7f800000u;   // +inf bits
    }
}

// ---------------- kernel 2: fp8 Gram + distance + masked reductions (triangular) ----------------
// SESSION CHAMPION (R14/R19, 39.5/39.7 us total; reproduced): 528 triangular
// 128x128 tiles, 3-buffer depth-2 prefetch, counted vmcnt(4) + raw s_barrier,
// one barrier per K-step, never vmcnt(0) until the last step. 50 KB LDS.
// sq exact fp32; only the Gram cross-term is fp8-quantized (absmax 0.0).

__global__ __launch_bounds__(256) void tile_kernel(
    const u8* __restrict__ bf8, const int* __restrict__ lab,
    const float* __restrict__ sq, float* __restrict__ ap_sum, u32* __restrict__ an_min)
{
    __shared__ u8 As[3][TILE_BYTES];
    __shared__ u8 Bs[3][TILE_BYTES];
    __shared__ float sqA[128], sqB[128];
    __shared__ int labA[128], labB[128];

    const int t = threadIdx.x;

    // XCD-chunked bijective swizzle: 528 % 8 == 0 -> each XCD gets 66 consecutive tiles
    int bid = blockIdx.x;
    bid = (bid & 7) * (NBLK / 8) + (bid >> 3);

    // triangular decode: bid -> (tm, tn), tm >= tn
    int tm = (int)((__builtin_sqrtf(8.0f * (float)bid + 1.0f) - 1.0f) * 0.5f);
    while ((tm + 1) * (tm + 2) / 2 <= bid) ++tm;
    while (tm * (tm + 1) / 2 > bid) --tm;
    const int tn = bid - tm * (tm + 1) / 2;
    const bool diag = (tm == tn);

    const int rowBase = tm * 128;
    const int colBase = tn * 128;

    if (t < 128) { labA[t] = lab[rowBase + t]; sqA[t] = sq[rowBase + t]; }
    else { int u = t - 128; labB[u] = lab[colBase + u]; sqB[u] = sq[colBase + u]; }

    const int wave = t >> 6, lane = t & 63;
    const int wr = wave >> 1, wc = wave & 1;
    const int g = lane >> 4, c = lane & 15;

    f32x4 acc[4][4];
    #pragma unroll
    for (int i = 0; i < 4; ++i)
        #pragma unroll
        for (int j = 0; j < 4; ++j)
            acc[i][j] = (f32x4){0.f, 0.f, 0.f, 0.f};

    const u8* gA = bf8 + (size_t)rowBase * D_SZ;
    const u8* gB = bf8 + (size_t)colBase * D_SZ;

    __syncthreads();   // lab/sq staged + vmcnt baseline 0 before pipeline starts

    // prologue: prefetch T0, T1 (8 vmem instructions in flight per wave)
    stage_fp8(gA,      As[0], t);
    stage_fp8(gB,      Bs[0], t);
    stage_fp8(gA + BK, As[1], t);
    stage_fp8(gB + BK, Bs[1], t);

    // fragment addressing: lane (c,g) reads 8 fp8 at K byte [ks*32 + g*8, +8) of
    // its row; stored 16B-chunk k16 = ks*2 + (g>>1) is XOR-swizzled by (row&3)=(c&3).
    const int x3 = c & 3, sub = (g & 1) * 8, gh = g >> 1;

    #pragma unroll
    for (int kk = 0; kk < NKK; ++kk) {
        if (kk < NKK - 1) { WAITV4(); }   // T(kk) landed (own wave); T(kk+1) still flying
        else              { WAITV0(); }   // last step: drain T(7)
        BARRIER();                        // all waves' T(kk) slices landed; kk-1 readers done

        if (kk + 2 < NKK) {               // depth-2 prefetch: safe, readers passed barrier
            stage_fp8(gA + (kk + 2) * BK, As[(kk + 2) % 3], t);
            stage_fp8(gB + (kk + 2) * BK, Bs[(kk + 2) % 3], t);
        }

        const u8* abuf = As[kk % 3];
        const u8* bbuf = Bs[kk % 3];

        #pragma unroll
        for (int ks = 0; ks < 2; ++ks) {
            const int koff = (((ks * 2 + gh) ^ x3) << 4) + sub;
            long a[4], b[4];
            #pragma unroll
            for (int mi = 0; mi < 4; ++mi)
                a[mi] = *(const long*)(abuf + (wr * 64 + mi * 16 + c) * BK + koff);
            #pragma unroll
            for (int ni = 0; ni < 4; ++ni)
                b[ni] = *(const long*)(bbuf + (wc * 64 + ni * 16 + c) * BK + koff);
            #pragma unroll
            for (int mi = 0; mi < 4; ++mi)
                #pragma unroll
                for (int ni = 0; ni < 4; ++ni)
                    acc[mi][ni] = __builtin_amdgcn_mfma_f32_16x16x32_fp8_fp8(a[mi], b[ni], acc[mi][ni], 0, 0, 0);
        }
    }

    // Epilogue. C/D layout (shape-determined, dtype-independent on gfx950):
    // col = lane&15, row = (lane>>4)*4 + reg.
    float sc[4], mc[4];
    #pragma unroll
    for (int ni = 0; ni < 4; ++ni) { sc[ni] = 0.0f; mc[ni] = __builtin_inff(); }

    #pragma unroll
    for (int mi = 0; mi < 4; ++mi) {
        #pragma unroll
        for (int r = 0; r < 4; ++r) {
            const int lrow = wr * 64 + mi * 16 + g * 4 + r;
            const int i = rowBase + lrow;
            const int li = labA[lrow];
            const float sqi = sqA[lrow];
            float s = 0.0f;
            float mn = __builtin_inff();
            #pragma unroll
            for (int ni = 0; ni < 4; ++ni) {
                const int lcol = wc * 64 + ni * 16 + c;
                float d2 = sqi + sqB[lcol] - 2.0f * acc[mi][ni][r];
                d2 = fmaxf(d2, 0.0f);
                float dist = (d2 > 1e-12f) ? __builtin_sqrtf(d2) : 0.0f;
                if (diag && lrow == lcol) dist = 0.0f;   // self distance exactly 0
                if (li == labB[lcol]) { s += dist; sc[ni] += dist; }
                else                  { mn = fminf(mn, dist); mc[ni] = fminf(mc[ni], dist); }
            }
            // row-side: reduce across the 16 c-lanes of this g-group
            #pragma unroll
            for (int off = 1; off < 16; off <<= 1) {
                s += __shfl_xor(s, off);
                mn = fminf(mn, __shfl_xor(mn, off));
            }
            if (c == 0) {
                atomicAdd(&ap_sum[i], s);
                atomicMin(&an_min[i], __float_as_uint(mn));   // dist >= 0: uint order == float order
            }
        }
    }

    if (!diag) {
        // column-side: reduce across the 4 g-groups, then atomic per column
        #pragma unroll
        for (int ni = 0; ni < 4; ++ni) {
            float s = sc[ni], mn = mc[ni];
            s += __shfl_xor(s, 16); s += __shfl_xor(s, 32);
            mn = fminf(mn, __shfl_xor(mn, 16)); mn = fminf(mn, __shfl_xor(mn, 32));
            if (lane < 16) {
                const int j = colBase + wc * 64 + ni * 16 + c;
                atomicAdd(&ap_sum[j], s);
                atomicMin(&an_min[j], __float_as_uint(mn));
            }
        }
    }
}

// ---------------- kernel 3: finalize scalar loss (single block, self-sufficient) ----------------
// Separate launch = device-wide visibility of tile_kernel's atomics without
// per-block fences (R12: 528 threadfences cost ~+10 us).

__global__ __launch_bounds__(1024) void final_kernel(
    const float* __restrict__ ap_sum, const u32* __restrict__ an_min,
    const int* __restrict__ lab, float* __restrict__ out)
{
    __shared__ int cnt[NCLS];
    __shared__ float wsum[16];
    const int t = threadIdx.x;
    if (t < NCLS) cnt[t] = 0;
    __syncthreads();
    for (int i = t; i < B_SZ; i += 1024) atomicAdd(&cnt[lab[i]], 1);
    __syncthreads();
    float v = 0.0f;
    for (int i = t; i < B_SZ; i += 1024) {
        float apm = ap_sum[i] / (float)cnt[lab[i]];
        float anm = __uint_as_float(an_min[i]);
        v += fmaxf(apm - anm + 1.0f, 0.0f);   // MARGIN = 1.0
    }
    #pragma unroll
    for (int off = 1; off < 64; off <<= 1) v += __shfl_xor(v, off);
    if ((t & 63) == 0) wsum[t >> 6] = v;
    __syncthreads();
    if (t == 0) {
        float s = 0.0f;
        #pragma unroll
        for (int w = 0; w < 16; ++w) s += wsum[w];
        out[0] = s;
    }
}

// ---------------- launch ----------------

extern "C" void kernel_launch(void* const* d_in, const int* in_sizes, int n_in,
                              void* d_out, int out_size, void* d_ws, size_t ws_size,
                              hipStream_t stream) {
    const float* inputs = (const float*)d_in[0];
    const int* labels = (const int*)d_in[1];
    float* out = (float*)d_out;

    // workspace layout (~2.1 MB)
    char* ws = (char*)d_ws;
    float* ap_sum = (float*)ws;            // 4096 floats
    u32* an_min = (u32*)(ws + 16384);      // 4096 u32
    float* sq = (float*)(ws + 32768);      // 4096 floats
    u8* bf8 = (u8*)(ws + 65536);           // 4096*512 fp8 = 2 MB

    prep_kernel<<<dim3(B_SZ / 4), dim3(256), 0, stream>>>(inputs, bf8, sq, ap_sum, an_min);
    tile_kernel<<<dim3(NBLK), dim3(256), 0, stream>>>(bf8, labels, sq, ap_sum, an_min);
    final_kernel<<<dim3(1), dim3(1024), 0, stream>>>(ap_sum, an_min, labels, out);
}